// Round 7
// baseline (1197.495 us; speedup 1.0000x reference)
//
#include <hip/hip_runtime.h>
#include <hip/hip_bf16.h>
#include <stdint.h>

// Problem constants
#define NBATCH 16
#define NPTS   4096
#define NPT    1024     // NPOINT
#define NSMP   64       // NSAMPLE
#define R2     0.04f    // RADIUS^2
#define ICH    9
#define OC1    64
#define OC2    64
#define OC3    128
#define NROWS  (NBATCH*NPT*NSMP)   // 1048576
#define NBLK1  (NROWS/256)         // 4096 blocks, pass-1
#define NBLK23 (NROWS/128)         // 8192 blocks, pass-2/3
#define NTOTF  1048576.0f

typedef __attribute__((ext_vector_type(8))) short short8;   // 8 bf16 (4 VGPR)
typedef __attribute__((ext_vector_type(4))) float f32x4;
typedef __attribute__((ext_vector_type(2))) float f32x2;    // v_pk_* pair

__device__ __forceinline__ short f2bf(float f) {
    __hip_bfloat16 h = __float2bfloat16(f);
    return *reinterpret_cast<short*>(&h);
}

// 64-bit max-combine with a DPP-moved copy (row_shr / row_bcast reduction).
#define DPP64_MAX(k, CTRL, RM) do {                                          \
    unsigned _lo = (unsigned)(k); unsigned _hi = (unsigned)((k) >> 32);      \
    unsigned _nlo = (unsigned)__builtin_amdgcn_update_dpp((int)_lo, (int)_lo,\
                                                    CTRL, RM, 0xF, false);   \
    unsigned _nhi = (unsigned)__builtin_amdgcn_update_dpp((int)_hi, (int)_hi,\
                                                    CTRL, RM, 0xF, false);   \
    unsigned long long _nk = ((unsigned long long)_nhi << 32) | _nlo;        \
    if (_nk > (k)) (k) = _nk;                                                \
} while (0)

// ---------------------------------------------------------------------------
// Kernel 1: farthest point sampling, v6 — BARRIER-FREE hot loop.
// One block per batch, 256 thr x 16 CONTIGUOUS pts (p = tid*16+j).
// Per step: packed dist update -> local value tree (lmax) -> local
// first-match scan (min local idx with dd==lmax, descending loop) ->
// u64 (lmax_bits, ~idx) DPP wave reduce (R4/R5-validated ctrl sequence)
// -> lane 63 publishes wave key to LDS -> threadfence_block (lgkmcnt
// drain orders key before tag) -> lane 0 posts monotone tag -> all
// threads spin on 4 volatile tags -> read 4 keys (volatile), 3 u64 max,
// decode far, broadcast ds_read_b128 centroid. No __syncthreads in loop.
// Safety: tags monotone + single-writer; dbuf key slots: a wave reaches
// it+2 (overwriting slot it&1) only after all waves posted tag it+2,
// which follows their consumption of iteration it's keys -> no overwrite
// race. Tags re-zeroed each launch before the single pre-loop barrier.
// Semantics: same per-point IEEE dist ops and same global (dist, min-idx)
// tie-break as all passing versions -> identical selection sequence.
// ---------------------------------------------------------------------------
__global__ __launch_bounds__(256) void k_fps(const float* __restrict__ xyz,
                                             float* __restrict__ newxyz)
{
    const int b    = blockIdx.x;
    const int tid  = threadIdx.x;
    const int wv   = tid >> 6;
    const int lane = tid & 63;
    const float* X = xyz + (size_t)b * NPTS * 3;

    __shared__ __align__(16) float sxyz[NPTS * 4];   // 64 KB packed points
    __shared__ float scf[NPT * 3];                   // 12 KB centroid trace
    __shared__ unsigned long long sKeyD[2][4];       // dbuf wave keys
    __shared__ volatile unsigned sTag[4];            // monotone wave tags

    const int p0 = tid * 16;                 // 16 contiguous points/thread
    f32x2 px[8], py[8], pz[8], dd[8];
    {
        // 16 pts = 48 floats = 12 aligned float4 loads
        const f32x4* src = (const f32x4*)(X + (size_t)p0 * 3);
        float c[48];
#pragma unroll
        for (int q = 0; q < 12; ++q) *(f32x4*)&c[q*4] = src[q];
#pragma unroll
        for (int m = 0; m < 8; ++m) {
            px[m] = (f32x2){c[6*m+0], c[6*m+3]};
            py[m] = (f32x2){c[6*m+1], c[6*m+4]};
            pz[m] = (f32x2){c[6*m+2], c[6*m+5]};
            dd[m] = (f32x2){1e10f, 1e10f};           // reference init
        }
#pragma unroll
        for (int j = 0; j < 16; ++j) {
            *(f32x4*)&sxyz[(p0 + j) * 4] =
                (f32x4){c[3*j+0], c[3*j+1], c[3*j+2], 0.f};
        }
    }
    if (tid < 4) sTag[tid] = 0u;
    __syncthreads();                         // only barrier before the loop

    // initial centroid = point 0 (same floats as X[0..2])
    float cx = sxyz[0], cy = sxyz[1], cz = sxyz[2];

    for (int it = 0; it < NPT; ++it) {
        const int buf = it & 1;
        if (tid == 0) {                      // LDS-only trace write
            scf[it*3+0] = cx; scf[it*3+1] = cy; scf[it*3+2] = cz;
        }
        const f32x2 c2x = (f32x2){cx, cx};
        const f32x2 c2y = (f32x2){cy, cy};
        const f32x2 c2z = (f32x2){cz, cz};
#pragma unroll
        for (int m = 0; m < 8; ++m) {
            f32x2 dx = px[m] - c2x, dy = py[m] - c2y, dz = pz[m] - c2z;
            f32x2 d  = dx*dx + dy*dy + dz*dz;        // same per-elem IEEE ops
            dd[m] = __builtin_elementwise_min(dd[m], d);
        }
        // local value max tree (exact: max associative)
        f32x2 t0 = __builtin_elementwise_max(dd[0], dd[1]);
        f32x2 t1 = __builtin_elementwise_max(dd[2], dd[3]);
        f32x2 t2 = __builtin_elementwise_max(dd[4], dd[5]);
        f32x2 t3 = __builtin_elementwise_max(dd[6], dd[7]);
        f32x2 u0 = __builtin_elementwise_max(t0, t1);
        f32x2 u1 = __builtin_elementwise_max(t2, t3);
        f32x2 v  = __builtin_elementwise_max(u0, u1);
        const float lmax = fmaxf(v.x, v.y);
        // first-match scan vs own lmax: descending so the LAST hit is the
        // smallest local index -> cand = ~min_idx (max comp = min idx)
        unsigned cand = 0u;
#pragma unroll
        for (int m = 7; m >= 0; --m) {
            if (dd[m].y == lmax) cand = 0xFFFFFFFFu - (unsigned)(p0 + 2*m + 1);
            if (dd[m].x == lmax) cand = 0xFFFFFFFFu - (unsigned)(p0 + 2*m + 0);
        }
        unsigned long long key =
            ((unsigned long long)__float_as_uint(lmax) << 32) | cand;
        DPP64_MAX(key, 0x111, 0xF);
        DPP64_MAX(key, 0x112, 0xF);
        DPP64_MAX(key, 0x114, 0xF);
        DPP64_MAX(key, 0x118, 0xF);
        DPP64_MAX(key, 0x142, 0xA);
        DPP64_MAX(key, 0x143, 0xC);

        if (lane == 63) sKeyD[buf][wv] = key;   // publish wave key
        __threadfence_block();                  // key visible before tag
        if (lane == 0) sTag[wv] = (unsigned)(it + 1);

        const unsigned need = (unsigned)(it + 1);
        for (;;) {                              // spin on monotone tags
            unsigned g0 = sTag[0], g1 = sTag[1], g2 = sTag[2], g3 = sTag[3];
            if (g0 >= need && g1 >= need && g2 >= need && g3 >= need) break;
        }
        volatile unsigned long long* kp = sKeyD[buf];
        unsigned long long k0 = kp[0], k1 = kp[1], k2 = kp[2], k3 = kp[3];
        unsigned long long m01 = k0 > k1 ? k0 : k1;
        unsigned long long m23 = k2 > k3 ? k2 : k3;
        unsigned long long bb  = m01 > m23 ? m01 : m23;
        const int far = (int)(0xFFFFFFFFu - (unsigned)(bb & 0xFFFFFFFFull));
        const f32x4 c4 = *(const f32x4*)&sxyz[far*4];   // one ds_read_b128
        cx = c4.x; cy = c4.y; cz = c4.z;
    }

    __syncthreads();
    // coalesced epilogue dump of the centroid trace
    float* outb = newxyz + (size_t)b * NPT * 3;
    for (int i = tid; i < NPT*3; i += 256) outb[i] = scf[i];
}

// ---------------------------------------------------------------------------
// Kernel 2: ball query + gather (unchanged). x0[row][9] f32.
// ---------------------------------------------------------------------------
__global__ __launch_bounds__(256) void k_ballq(const float* __restrict__ xyz,
                                               const float* __restrict__ pts,
                                               const float* __restrict__ newxyz,
                                               float* __restrict__ x0)
{
    const int wave = threadIdx.x >> 6;
    const int lane = threadIdx.x & 63;
    const int g = blockIdx.x * 4 + wave;
    const int b = g >> 10;
    const float* X = xyz + (size_t)b * NPTS * 3;
    const float* P = pts + (size_t)b * NPTS * 6;
    const float cx = newxyz[(size_t)g*3+0];
    const float cy = newxyz[(size_t)g*3+1];
    const float cz = newxyz[(size_t)g*3+2];
    const float sn = cx*cx + cy*cy + cz*cz;

    __shared__ int sFirst[4];
    int total = 0;
    for (int chunk = 0; chunk < NPTS/64; ++chunk) {
        int p = chunk*64 + lane;
        float x = X[p*3+0], y = X[p*3+1], z = X[p*3+2];
        float sp  = x*x + y*y + z*z;
        float dot = cx*x + cy*y + cz*z;
        float sqr = (sn + sp) - 2.0f*dot;
        bool inb = !(sqr > R2);
        unsigned long long mask = __ballot(inb);
        int before = __popcll(mask & ((1ull << lane) - 1ull));
        int pos = total + before;
        if (inb && pos < NSMP) {
            if (pos == 0) sFirst[wave] = p;
            float* row = x0 + ((size_t)g * NSMP + pos) * ICH;
            row[0] = x - cx; row[1] = y - cy; row[2] = z - cz;
#pragma unroll
            for (int c = 0; c < 6; ++c) row[3+c] = P[(size_t)p*6 + c];
        }
        total += (int)__popcll(mask);
        if (total >= NSMP) break;
    }
    if (total < NSMP) {
        int first = sFirst[wave];
        float x = X[first*3+0], y = X[first*3+1], z = X[first*3+2];
        float r0 = x - cx, r1 = y - cy, r2 = z - cz;
        float q0 = P[(size_t)first*6+0], q1 = P[(size_t)first*6+1], q2 = P[(size_t)first*6+2];
        float q3 = P[(size_t)first*6+3], q4 = P[(size_t)first*6+4], q5 = P[(size_t)first*6+5];
        for (int slot = total + lane; slot < NSMP; slot += 64) {
            float* row = x0 + ((size_t)g * NSMP + slot) * ICH;
            row[0]=r0; row[1]=r1; row[2]=r2;
            row[3]=q0; row[4]=q1; row[5]=q2; row[6]=q3; row[7]=q4; row[8]=q5;
        }
    }
}

// ---------------------------------------------------------------------------
// Weight prep: pack w1 (64x64) and w2 (128x64) into bf16 MFMA B-fragment
// order. Frag f = n*2 + kblk; entry (lane l, j): w[(n*16+(l&15))*64 +
// kblk*32 + (l>>4)*8 + j].
// ---------------------------------------------------------------------------
__global__ __launch_bounds__(256) void k_prep(const float* __restrict__ w1,
                                              const float* __restrict__ w2,
                                              short* __restrict__ w1f,
                                              short* __restrict__ w2f)
{
    int t = blockIdx.x * 256 + threadIdx.x;
    if (t < 8*64) {
        int f = t >> 6, l = t & 63;
        int n = f >> 1, kb = f & 1;
        int col = n*16 + (l & 15);
        int k0  = kb*32 + (l >> 4)*8;
#pragma unroll
        for (int j = 0; j < 8; ++j)
            w1f[((size_t)t)*8 + j] = f2bf(w1[col*64 + k0 + j]);
    } else if (t < 8*64 + 16*64) {
        int t2 = t - 8*64;
        int f = t2 >> 6, l = t2 & 63;
        int n = f >> 1, kb = f & 1;
        int col = n*16 + (l & 15);
        int k0  = kb*32 + (l >> 4)*8;
#pragma unroll
        for (int j = 0; j < 8; ++j)
            w2f[((size_t)t2)*8 + j] = f2bf(w2[col*64 + k0 + j]);
    }
}

// ---------------------------------------------------------------------------
// Pass-1 stats: 256 rows/block, f32 VALU layer 1, LDS-transposed per-channel
// sum/sumsq partials.
// ---------------------------------------------------------------------------
__global__ __launch_bounds__(256) void k_mlp1(
    const float* __restrict__ x0,
    const float* __restrict__ w0, const float* __restrict__ b0,
    float* __restrict__ pSum, float* __restrict__ pSq)
{
    __shared__ float staged[32 * 256];
    const int tid = threadIdx.x;
    const int bid = blockIdx.x;
    const size_t row = (size_t)bid * 256 + tid;

    float x[ICH];
    const float* xr = x0 + row * ICH;
#pragma unroll
    for (int c = 0; c < ICH; ++c) x[c] = xr[c];

    float h1[OC1];
#pragma unroll
    for (int o = 0; o < OC1; ++o) {
        float a = b0[o];
#pragma unroll
        for (int c = 0; c < ICH; ++c) a += w0[o*ICH + c] * x[c];
        h1[o] = a;
    }
#pragma unroll
    for (int cb = 0; cb < OC1; cb += 32) {
        __syncthreads();
#pragma unroll
        for (int o = 0; o < 32; ++o) staged[o*256 + tid] = h1[cb + o];
        __syncthreads();
        const int ch = tid >> 3, seg = tid & 7;
        const float* col = staged + ch*256 + seg*32;
        float s1 = 0.f, s2 = 0.f;
#pragma unroll
        for (int i = 0; i < 32; ++i) {
            float vv = col[(i + tid) & 31];
            s1 += vv; s2 += vv*vv;
        }
#pragma unroll
        for (int m = 1; m < 8; m <<= 1) {
            s1 += __shfl_xor(s1, m, 64);
            s2 += __shfl_xor(s2, m, 64);
        }
        if (seg == 0) {
            pSum[(size_t)bid*OC1 + cb + ch] = s1;
            pSq [(size_t)bid*OC1 + cb + ch] = s2;
        }
    }
}

// ---------------------------------------------------------------------------
// MFMA passes 2/3 (unchanged from passing round-3 version).
// ---------------------------------------------------------------------------
template<int DEPTH>
__global__ __launch_bounds__(256) void k_mlp23(
    const float* __restrict__ x0,
    const float* __restrict__ w0, const float* __restrict__ b0,
    const short* __restrict__ w1f, const float* __restrict__ b1,
    const short* __restrict__ w2f, const float* __restrict__ b2,
    const float* __restrict__ AC,
    float* __restrict__ pSum, float* __restrict__ pSq,
    float* __restrict__ maxk)
{
    __shared__ __align__(16) short h1s[128*64];   // 16 KB, swizzled
    __shared__ __align__(16) short h2s[128*64];   // 16 KB
    __shared__ __align__(16) short w1s[8*64*8];   // 8 KB, frag order
    __shared__ __align__(16) short w2s[16*64*8];  // 16 KB
    __shared__ float sS[4][128];
    __shared__ float sQ[4][128];
    __shared__ float sM[4][128];

    const int tid = threadIdx.x;
    const int bid = blockIdx.x;

    // stage weight fragments (linear, conflict-free 16B chunks)
    {
        const uint4* s1 = (const uint4*)w1f;
        uint4* d1 = (uint4*)w1s;
        for (int i = tid; i < 512; i += 256) d1[i] = s1[i];
        if (DEPTH == 3) {
            const uint4* s2 = (const uint4*)w2f;
            uint4* d2 = (uint4*)w2s;
            for (int i = tid; i < 1024; i += 256) d2[i] = s2[i];
        }
    }

    // ---- Phase A: layer 1 on VALU, affine+relu, bf16, swizzled LDS store.
    {
        const int rloc = tid & 127;
        const int half = __builtin_amdgcn_readfirstlane(tid >> 7);
        const size_t rowg = (size_t)bid * 128 + rloc;
        const float* xr = x0 + rowg * ICH;
        float x[ICH];
#pragma unroll
        for (int c = 0; c < ICH; ++c) x[c] = xr[c];
        const float* w0h = w0 + half*32*ICH;
        const float* b0h = b0 + half*32;
        const float* Ah  = AC + half*32;
        const float* Ch  = AC + 64 + half*32;
        float h[32];
#pragma unroll
        for (int o = 0; o < 32; ++o) {
            float a = b0h[o];
#pragma unroll
            for (int c = 0; c < ICH; ++c) a += w0h[o*ICH + c] * x[c];
            h[o] = fmaxf(Ah[o]*a + Ch[o], 0.0f);
        }
#pragma unroll
        for (int q = 0; q < 4; ++q) {
            short8 v;
#pragma unroll
            for (int j = 0; j < 8; ++j) v[j] = f2bf(h[q*8 + j]);
            int byte = (rloc*128 + half*64 + q*16) ^ ((rloc & 7) << 4);
            *(short8*)((char*)h1s + byte) = v;
        }
    }
    __syncthreads();

    // ---- Phase B: layer 2 MFMA
    const int wv = tid >> 6;
    const int l  = tid & 63;
    const int lr = l & 15, lk = l >> 4;

    f32x4 acc2[2][4];
    const f32x4 fz = {0.f, 0.f, 0.f, 0.f};
#pragma unroll
    for (int m = 0; m < 2; ++m)
#pragma unroll
        for (int n = 0; n < 4; ++n) acc2[m][n] = fz;

    short8 afr[2][2];
#pragma unroll
    for (int m = 0; m < 2; ++m)
#pragma unroll
        for (int kb = 0; kb < 2; ++kb) {
            int row = wv*32 + m*16 + lr;
            int byte = (row*128 + (kb*4 + lk)*16) ^ ((row & 7) << 4);
            afr[m][kb] = *(short8*)((char*)h1s + byte);
        }
#pragma unroll
    for (int n = 0; n < 4; ++n) {
        short8 bf0 = *(short8*)(w1s + ((n*2+0)*64 + l)*8);
        short8 bf1 = *(short8*)(w1s + ((n*2+1)*64 + l)*8);
#pragma unroll
        for (int m = 0; m < 2; ++m) {
            acc2[m][n] = __builtin_amdgcn_mfma_f32_16x16x32_bf16(afr[m][0], bf0, acc2[m][n], 0, 0, 0);
            acc2[m][n] = __builtin_amdgcn_mfma_f32_16x16x32_bf16(afr[m][1], bf1, acc2[m][n], 0, 0, 0);
        }
    }
    // bias
#pragma unroll
    for (int n = 0; n < 4; ++n) {
        float bb = b1[n*16 + lr];
#pragma unroll
        for (int m = 0; m < 2; ++m)
#pragma unroll
            for (int r = 0; r < 4; ++r) acc2[m][n][r] += bb;
    }

    if (DEPTH == 2) {
#pragma unroll
        for (int n = 0; n < 4; ++n) {
            float s1 = 0.f, s2 = 0.f;
#pragma unroll
            for (int m = 0; m < 2; ++m)
#pragma unroll
                for (int r = 0; r < 4; ++r) {
                    float v = acc2[m][n][r];
                    s1 += v; s2 += v*v;
                }
            s1 += __shfl_xor(s1, 16, 64); s1 += __shfl_xor(s1, 32, 64);
            s2 += __shfl_xor(s2, 16, 64); s2 += __shfl_xor(s2, 32, 64);
            if (l < 16) { sS[wv][n*16 + l] = s1; sQ[wv][n*16 + l] = s2; }
        }
        __syncthreads();
        if (tid < OC2) {
            float a = 0.f, q = 0.f;
#pragma unroll
            for (int w = 0; w < 4; ++w) { a += sS[w][tid]; q += sQ[w][tid]; }
            pSum[(size_t)bid*OC2 + tid] = a;
            pSq [(size_t)bid*OC2 + tid] = q;
        }
        return;
    }

    // ---- DEPTH == 3: affine+relu -> bf16 h2 -> LDS (same swizzle)
#pragma unroll
    for (int n = 0; n < 4; ++n) {
        int c = n*16 + lr;
        float A2 = AC[128 + c], C2 = AC[192 + c];
#pragma unroll
        for (int m = 0; m < 2; ++m)
#pragma unroll
            for (int r = 0; r < 4; ++r) {
                float v = fmaxf(A2*acc2[m][n][r] + C2, 0.0f);
                int row = wv*32 + m*16 + lk*4 + r;
                int byte = (row*128 + c*2) ^ ((row & 7) << 4);
                *(short*)((char*)h2s + byte) = f2bf(v);
            }
    }
    __syncthreads();

    // ---- Phase C: layer 3 MFMA
    f32x4 acc3[2][8];
#pragma unroll
    for (int m = 0; m < 2; ++m)
#pragma unroll
        for (int n = 0; n < 8; ++n) acc3[m][n] = fz;

    short8 afr2[2][2];
#pragma unroll
    for (int m = 0; m < 2; ++m)
#pragma unroll
        for (int kb = 0; kb < 2; ++kb) {
            int row = wv*32 + m*16 + lr;
            int byte = (row*128 + (kb*4 + lk)*16) ^ ((row & 7) << 4);
            afr2[m][kb] = *(short8*)((char*)h2s + byte);
        }
#pragma unroll
    for (int n = 0; n < 8; ++n) {
        short8 bf0 = *(short8*)(w2s + ((n*2+0)*64 + l)*8);
        short8 bf1 = *(short8*)(w2s + ((n*2+1)*64 + l)*8);
#pragma unroll
        for (int m = 0; m < 2; ++m) {
            acc3[m][n] = __builtin_amdgcn_mfma_f32_16x16x32_bf16(afr2[m][0], bf0, acc3[m][n], 0, 0, 0);
            acc3[m][n] = __builtin_amdgcn_mfma_f32_16x16x32_bf16(afr2[m][1], bf1, acc3[m][n], 0, 0, 0);
        }
    }

    // stats + per-wave (32-row) col max
#pragma unroll
    for (int n = 0; n < 8; ++n) {
        float bb = b2[n*16 + lr];
        float s1 = 0.f, s2 = 0.f, mx = -3.0e38f;
#pragma unroll
        for (int m = 0; m < 2; ++m)
#pragma unroll
            for (int r = 0; r < 4; ++r) {
                float v = acc3[m][n][r] + bb;
                s1 += v; s2 += v*v; mx = fmaxf(mx, v);
            }
        s1 += __shfl_xor(s1, 16, 64); s1 += __shfl_xor(s1, 32, 64);
        s2 += __shfl_xor(s2, 16, 64); s2 += __shfl_xor(s2, 32, 64);
        mx = fmaxf(mx, __shfl_xor(mx, 16, 64));
        mx = fmaxf(mx, __shfl_xor(mx, 32, 64));
        if (l < 16) {
            sS[wv][n*16 + l] = s1;
            sQ[wv][n*16 + l] = s2;
            sM[wv][n*16 + l] = mx;
        }
    }
    __syncthreads();
    if (tid < OC3) {
        float a = 0.f, q = 0.f;
#pragma unroll
        for (int w = 0; w < 4; ++w) { a += sS[w][tid]; q += sQ[w][tid]; }
        pSum[(size_t)bid*OC3 + tid] = a;
        pSq [(size_t)bid*OC3 + tid] = q;
    }
    {
        int g = tid >> 7, c = tid & 127;   // 2 groups of 64 rows per block
        maxk[((size_t)bid*2 + g)*OC3 + c] = fmaxf(sM[2*g][c], sM[2*g+1][c]);
    }
}

// ---------------------------------------------------------------------------
// Finalize BN affine: A = g*rsqrt(var+eps), C = be - mean*A.
// ---------------------------------------------------------------------------
__global__ __launch_bounds__(256) void k_finalize(
    const float* __restrict__ pSum, const float* __restrict__ pSq,
    const float* __restrict__ g, const float* __restrict__ be,
    float* __restrict__ A, float* __restrict__ C, int OC, int nblk)
{
    const int o = blockIdx.x, tid = threadIdx.x;
    float s1 = 0.f, s2 = 0.f;
    for (int i = tid; i < nblk; i += 256) {
        s1 += pSum[(size_t)i*OC + o];
        s2 += pSq [(size_t)i*OC + o];
    }
    __shared__ float r1[256], r2[256];
    r1[tid] = s1; r2[tid] = s2;
    __syncthreads();
    for (int s = 128; s > 0; s >>= 1) {
        if (tid < s) { r1[tid] += r1[tid+s]; r2[tid] += r2[tid+s]; }
        __syncthreads();
    }
    if (tid == 0) {
        float mean = r1[0] * (1.0f / NTOTF);
        float var  = r2[0] * (1.0f / NTOTF) - mean*mean;
        float a = g[o] / sqrtf(var + 1e-5f);
        A[o] = a;
        C[o] = be[o] - mean * a;
    }
}

// ---------------------------------------------------------------------------
// Final output: out1[b][ch][s] = relu(A3[ch]*maxk[b*NPT+s][ch] + C3[ch])
// ---------------------------------------------------------------------------
__global__ __launch_bounds__(256) void k_out(const float* __restrict__ maxk,
                                             const float* __restrict__ A,
                                             const float* __restrict__ C,
                                             float* __restrict__ out1)
{
    int idx = blockIdx.x * 256 + threadIdx.x;
    int s  = idx & (NPT - 1);
    int ch = (idx >> 10) & (OC3 - 1);
    int b  = idx >> 17;
    float v = maxk[((size_t)(b * NPT + s)) * OC3 + ch];
    out1[idx] = fmaxf(A[ch] * v + C[ch], 0.0f);
}

// ---------------------------------------------------------------------------
extern "C" void kernel_launch(void* const* d_in, const int* in_sizes, int n_in,
                              void* d_out, int out_size, void* d_ws, size_t ws_size,
                              hipStream_t stream)
{
    const float* xyz = (const float*)d_in[0];
    const float* pts = (const float*)d_in[1];
    const float* w0  = (const float*)d_in[2];
    const float* b0  = (const float*)d_in[3];
    const float* g0  = (const float*)d_in[4];
    const float* be0 = (const float*)d_in[5];
    const float* w1  = (const float*)d_in[6];
    const float* b1  = (const float*)d_in[7];
    const float* g1  = (const float*)d_in[8];
    const float* be1 = (const float*)d_in[9];
    const float* w2  = (const float*)d_in[10];
    const float* b2  = (const float*)d_in[11];
    const float* g2  = (const float*)d_in[12];
    const float* be2 = (const float*)d_in[13];

    float* out0 = (float*)d_out;                     // new_xyz (16,1024,3)
    float* out1 = out0 + (size_t)NBATCH*NPT*3;       // new_points (16,128,1024)

    // Workspace layout (floats). ~52 MB.
    float* ws   = (float*)d_ws;
    float* x0   = ws;                                  // 9,437,184
    float* pSum = x0   + (size_t)NROWS*ICH;            // 1,048,576 (8192*128)
    float* pSq  = pSum + (size_t)NBLK23*OC3;           // 1,048,576
    float* AC   = pSq  + (size_t)NBLK23*OC3;           // 512
    float* maxk = AC + 512;                            // 2,097,152
    short* w1f  = (short*)(maxk + (size_t)NBATCH*NPT*OC3);   // 4096 shorts
    short* w2f  = w1f + 8*64*8;                        // 8192 shorts

    k_prep <<<6, 256, 0, stream>>>(w1, w2, w1f, w2f);
    k_fps  <<<NBATCH, 256, 0, stream>>>(xyz, out0);
    k_ballq<<<(NBATCH*NPT)/4, 256, 0, stream>>>(xyz, pts, out0, x0);

    k_mlp1<<<NBLK1, 256, 0, stream>>>(x0, w0, b0, pSum, pSq);
    k_finalize<<<OC1, 256, 0, stream>>>(pSum, pSq, g0, be0, AC+0,   AC+64,  OC1, NBLK1);
    k_mlp23<2><<<NBLK23, 256, 0, stream>>>(x0, w0,b0, w1f,b1, w2f,b2, AC, pSum, pSq, maxk);
    k_finalize<<<OC2, 256, 0, stream>>>(pSum, pSq, g1, be1, AC+128, AC+192, OC2, NBLK23);
    k_mlp23<3><<<NBLK23, 256, 0, stream>>>(x0, w0,b0, w1f,b1, w2f,b2, AC, pSum, pSq, maxk);
    k_finalize<<<OC3, 256, 0, stream>>>(pSum, pSq, g2, be2, AC+256, AC+384, OC3, NBLK23);

    k_out<<<(NBATCH*OC3*NPT)/256, 256, 0, stream>>>(maxk, AC+256, AC+384, out1);
}

// Round 8
// 1179.814 us; speedup vs baseline: 1.0150x; 1.0150x over previous
//
#include <hip/hip_runtime.h>
#include <hip/hip_bf16.h>
#include <stdint.h>

// Problem constants
#define NBATCH 16
#define NPTS   4096
#define NPT    1024     // NPOINT
#define NSMP   64       // NSAMPLE
#define R2     0.04f    // RADIUS^2
#define ICH    9
#define OC1    64
#define OC2    64
#define OC3    128
#define NROWS  (NBATCH*NPT*NSMP)   // 1048576
#define NBLK1  (NROWS/256)         // 4096 blocks, pass-1
#define NBLK23 (NROWS/128)         // 8192 blocks, pass-2/3
#define NTOTF  1048576.0f

typedef __attribute__((ext_vector_type(8))) short short8;   // 8 bf16 (4 VGPR)
typedef __attribute__((ext_vector_type(4))) float f32x4;
typedef __attribute__((ext_vector_type(2))) float f32x2;    // v_pk_* pair

__device__ __forceinline__ short f2bf(float f) {
    __hip_bfloat16 h = __float2bfloat16(f);
    return *reinterpret_cast<short*>(&h);
}

// 64-bit max-combine with a DPP-moved copy (row_shr / row_bcast reduction).
#define DPP64_MAX(k, CTRL, RM) do {                                          \
    unsigned _lo = (unsigned)(k); unsigned _hi = (unsigned)((k) >> 32);      \
    unsigned _nlo = (unsigned)__builtin_amdgcn_update_dpp((int)_lo, (int)_lo,\
                                                    CTRL, RM, 0xF, false);   \
    unsigned _nhi = (unsigned)__builtin_amdgcn_update_dpp((int)_hi, (int)_hi,\
                                                    CTRL, RM, 0xF, false);   \
    unsigned long long _nk = ((unsigned long long)_nhi << 32) | _nlo;        \
    if (_nk > (k)) (k) = _nk;                                                \
} while (0)

// ---------------------------------------------------------------------------
// Kernel 1: farthest point sampling, v7. One block per batch, 128 thr (2
// waves) x 32 CONTIGUOUS pts/lane. Single __syncthreads per step (the
// cheapest block sync per R5/R6/R7 measurements). Per step:
//   packed dist update (112 pk ops) -> per-lane value tree (15 pk_max +
//   fmax -> lmax) -> descending equality scan (min local idx with
//   dd==lmax) -> ONE u64 (lmax_bits, ~p) key -> DPP64 wave reduce ->
//   2 wave partials in LDS -> barrier -> max of 2, decode far ->
//   broadcast ds_read_b128 centroid from packed LDS points.
// Semantics: identical per-point IEEE distance ops and identical global
// (dist, min-index) tie-break as all passing versions -> identical
// selection sequence. Centroid trace in LDS, dumped at the end.
// ---------------------------------------------------------------------------
__global__ __launch_bounds__(128) void k_fps(const float* __restrict__ xyz,
                                             float* __restrict__ newxyz)
{
    const int b    = blockIdx.x;
    const int tid  = threadIdx.x;
    const int wv   = tid >> 6;
    const int lane = tid & 63;
    const float* X = xyz + (size_t)b * NPTS * 3;

    __shared__ __align__(16) float sxyz[NPTS * 4];   // 64 KB packed points
    __shared__ float scf[NPT * 3];                   // 12 KB centroid trace
    __shared__ unsigned long long sKey[2][2];        // dbuf wave partials

    const int p0 = tid * 32;                 // 32 contiguous points/thread
    f32x2 px[16], py[16], pz[16], dd[16];
    {
        // 32 pts = 96 floats = 24 aligned float4 loads
        const f32x4* src = (const f32x4*)(X + (size_t)p0 * 3);
        float c[96];
#pragma unroll
        for (int q = 0; q < 24; ++q) *(f32x4*)&c[q*4] = src[q];
#pragma unroll
        for (int m = 0; m < 16; ++m) {
            px[m] = (f32x2){c[6*m+0], c[6*m+3]};
            py[m] = (f32x2){c[6*m+1], c[6*m+4]};
            pz[m] = (f32x2){c[6*m+2], c[6*m+5]};
            dd[m] = (f32x2){1e10f, 1e10f};           // reference init
        }
#pragma unroll
        for (int j = 0; j < 32; ++j) {
            *(f32x4*)&sxyz[(p0 + j) * 4] =
                (f32x4){c[3*j+0], c[3*j+1], c[3*j+2], 0.f};
        }
    }
    __syncthreads();

    // initial centroid = point 0 (same floats as X[0..2])
    float cx = sxyz[0], cy = sxyz[1], cz = sxyz[2];

    for (int it = 0; it < NPT; ++it) {
        const int buf = it & 1;
        if (tid == 0) {                      // LDS-only trace write
            scf[it*3+0] = cx; scf[it*3+1] = cy; scf[it*3+2] = cz;
        }
        const f32x2 c2x = (f32x2){cx, cx};
        const f32x2 c2y = (f32x2){cy, cy};
        const f32x2 c2z = (f32x2){cz, cz};
#pragma unroll
        for (int m = 0; m < 16; ++m) {
            f32x2 dx = px[m] - c2x, dy = py[m] - c2y, dz = pz[m] - c2z;
            f32x2 d  = dx*dx + dy*dy + dz*dz;        // same per-elem IEEE ops
            dd[m] = __builtin_elementwise_min(dd[m], d);
        }
        // per-lane value max tree (exact: max associative)
        f32x2 t0 = __builtin_elementwise_max(dd[0],  dd[1]);
        f32x2 t1 = __builtin_elementwise_max(dd[2],  dd[3]);
        f32x2 t2 = __builtin_elementwise_max(dd[4],  dd[5]);
        f32x2 t3 = __builtin_elementwise_max(dd[6],  dd[7]);
        f32x2 t4 = __builtin_elementwise_max(dd[8],  dd[9]);
        f32x2 t5 = __builtin_elementwise_max(dd[10], dd[11]);
        f32x2 t6 = __builtin_elementwise_max(dd[12], dd[13]);
        f32x2 t7 = __builtin_elementwise_max(dd[14], dd[15]);
        f32x2 u0 = __builtin_elementwise_max(t0, t1);
        f32x2 u1 = __builtin_elementwise_max(t2, t3);
        f32x2 u2 = __builtin_elementwise_max(t4, t5);
        f32x2 u3 = __builtin_elementwise_max(t6, t7);
        f32x2 v0 = __builtin_elementwise_max(u0, u1);
        f32x2 v1 = __builtin_elementwise_max(u2, u3);
        f32x2 v  = __builtin_elementwise_max(v0, v1);
        const float lmax = fmaxf(v.x, v.y);
        // descending equality scan: last hit = smallest local index
        unsigned cand = 0u;
#pragma unroll
        for (int m = 15; m >= 0; --m) {
            if (dd[m].y == lmax) cand = 0xFFFFFFFFu - (unsigned)(p0 + 2*m + 1);
            if (dd[m].x == lmax) cand = 0xFFFFFFFFu - (unsigned)(p0 + 2*m + 0);
        }
        unsigned long long key =
            ((unsigned long long)__float_as_uint(lmax) << 32) | cand;
        DPP64_MAX(key, 0x111, 0xF);
        DPP64_MAX(key, 0x112, 0xF);
        DPP64_MAX(key, 0x114, 0xF);
        DPP64_MAX(key, 0x118, 0xF);
        DPP64_MAX(key, 0x142, 0xA);
        DPP64_MAX(key, 0x143, 0xC);

        if (lane == 63) sKey[buf][wv] = key;
        __syncthreads();                     // single barrier per step
        unsigned long long k0 = sKey[buf][0];
        unsigned long long k1 = sKey[buf][1];
        unsigned long long bb = k0 > k1 ? k0 : k1;
        const int far = (int)(0xFFFFFFFFu - (unsigned)(bb & 0xFFFFFFFFull));
        const f32x4 c4 = *(const f32x4*)&sxyz[far*4];   // one ds_read_b128
        cx = c4.x; cy = c4.y; cz = c4.z;
    }

    __syncthreads();
    // coalesced epilogue dump of the centroid trace
    float* outb = newxyz + (size_t)b * NPT * 3;
    for (int i = tid; i < NPT*3; i += 128) outb[i] = scf[i];
}

// ---------------------------------------------------------------------------
// Kernel 2: ball query + gather (unchanged). x0[row][9] f32.
// ---------------------------------------------------------------------------
__global__ __launch_bounds__(256) void k_ballq(const float* __restrict__ xyz,
                                               const float* __restrict__ pts,
                                               const float* __restrict__ newxyz,
                                               float* __restrict__ x0)
{
    const int wave = threadIdx.x >> 6;
    const int lane = threadIdx.x & 63;
    const int g = blockIdx.x * 4 + wave;
    const int b = g >> 10;
    const float* X = xyz + (size_t)b * NPTS * 3;
    const float* P = pts + (size_t)b * NPTS * 6;
    const float cx = newxyz[(size_t)g*3+0];
    const float cy = newxyz[(size_t)g*3+1];
    const float cz = newxyz[(size_t)g*3+2];
    const float sn = cx*cx + cy*cy + cz*cz;

    __shared__ int sFirst[4];
    int total = 0;
    for (int chunk = 0; chunk < NPTS/64; ++chunk) {
        int p = chunk*64 + lane;
        float x = X[p*3+0], y = X[p*3+1], z = X[p*3+2];
        float sp  = x*x + y*y + z*z;
        float dot = cx*x + cy*y + cz*z;
        float sqr = (sn + sp) - 2.0f*dot;
        bool inb = !(sqr > R2);
        unsigned long long mask = __ballot(inb);
        int before = __popcll(mask & ((1ull << lane) - 1ull));
        int pos = total + before;
        if (inb && pos < NSMP) {
            if (pos == 0) sFirst[wave] = p;
            float* row = x0 + ((size_t)g * NSMP + pos) * ICH;
            row[0] = x - cx; row[1] = y - cy; row[2] = z - cz;
#pragma unroll
            for (int c = 0; c < 6; ++c) row[3+c] = P[(size_t)p*6 + c];
        }
        total += (int)__popcll(mask);
        if (total >= NSMP) break;
    }
    if (total < NSMP) {
        int first = sFirst[wave];
        float x = X[first*3+0], y = X[first*3+1], z = X[first*3+2];
        float r0 = x - cx, r1 = y - cy, r2 = z - cz;
        float q0 = P[(size_t)first*6+0], q1 = P[(size_t)first*6+1], q2 = P[(size_t)first*6+2];
        float q3 = P[(size_t)first*6+3], q4 = P[(size_t)first*6+4], q5 = P[(size_t)first*6+5];
        for (int slot = total + lane; slot < NSMP; slot += 64) {
            float* row = x0 + ((size_t)g * NSMP + slot) * ICH;
            row[0]=r0; row[1]=r1; row[2]=r2;
            row[3]=q0; row[4]=q1; row[5]=q2; row[6]=q3; row[7]=q4; row[8]=q5;
        }
    }
}

// ---------------------------------------------------------------------------
// Weight prep: pack w1 (64x64) and w2 (128x64) into bf16 MFMA B-fragment
// order. Frag f = n*2 + kblk; entry (lane l, j): w[(n*16+(l&15))*64 +
// kblk*32 + (l>>4)*8 + j].
// ---------------------------------------------------------------------------
__global__ __launch_bounds__(256) void k_prep(const float* __restrict__ w1,
                                              const float* __restrict__ w2,
                                              short* __restrict__ w1f,
                                              short* __restrict__ w2f)
{
    int t = blockIdx.x * 256 + threadIdx.x;
    if (t < 8*64) {
        int f = t >> 6, l = t & 63;
        int n = f >> 1, kb = f & 1;
        int col = n*16 + (l & 15);
        int k0  = kb*32 + (l >> 4)*8;
#pragma unroll
        for (int j = 0; j < 8; ++j)
            w1f[((size_t)t)*8 + j] = f2bf(w1[col*64 + k0 + j]);
    } else if (t < 8*64 + 16*64) {
        int t2 = t - 8*64;
        int f = t2 >> 6, l = t2 & 63;
        int n = f >> 1, kb = f & 1;
        int col = n*16 + (l & 15);
        int k0  = kb*32 + (l >> 4)*8;
#pragma unroll
        for (int j = 0; j < 8; ++j)
            w2f[((size_t)t2)*8 + j] = f2bf(w2[col*64 + k0 + j]);
    }
}

// ---------------------------------------------------------------------------
// Pass-1 stats: 256 rows/block, f32 VALU layer 1, LDS-transposed per-channel
// sum/sumsq partials.
// ---------------------------------------------------------------------------
__global__ __launch_bounds__(256) void k_mlp1(
    const float* __restrict__ x0,
    const float* __restrict__ w0, const float* __restrict__ b0,
    float* __restrict__ pSum, float* __restrict__ pSq)
{
    __shared__ float staged[32 * 256];
    const int tid = threadIdx.x;
    const int bid = blockIdx.x;
    const size_t row = (size_t)bid * 256 + tid;

    float x[ICH];
    const float* xr = x0 + row * ICH;
#pragma unroll
    for (int c = 0; c < ICH; ++c) x[c] = xr[c];

    float h1[OC1];
#pragma unroll
    for (int o = 0; o < OC1; ++o) {
        float a = b0[o];
#pragma unroll
        for (int c = 0; c < ICH; ++c) a += w0[o*ICH + c] * x[c];
        h1[o] = a;
    }
#pragma unroll
    for (int cb = 0; cb < OC1; cb += 32) {
        __syncthreads();
#pragma unroll
        for (int o = 0; o < 32; ++o) staged[o*256 + tid] = h1[cb + o];
        __syncthreads();
        const int ch = tid >> 3, seg = tid & 7;
        const float* col = staged + ch*256 + seg*32;
        float s1 = 0.f, s2 = 0.f;
#pragma unroll
        for (int i = 0; i < 32; ++i) {
            float vv = col[(i + tid) & 31];
            s1 += vv; s2 += vv*vv;
        }
#pragma unroll
        for (int m = 1; m < 8; m <<= 1) {
            s1 += __shfl_xor(s1, m, 64);
            s2 += __shfl_xor(s2, m, 64);
        }
        if (seg == 0) {
            pSum[(size_t)bid*OC1 + cb + ch] = s1;
            pSq [(size_t)bid*OC1 + cb + ch] = s2;
        }
    }
}

// ---------------------------------------------------------------------------
// MFMA passes 2/3 (unchanged from passing round-3 version).
// ---------------------------------------------------------------------------
template<int DEPTH>
__global__ __launch_bounds__(256) void k_mlp23(
    const float* __restrict__ x0,
    const float* __restrict__ w0, const float* __restrict__ b0,
    const short* __restrict__ w1f, const float* __restrict__ b1,
    const short* __restrict__ w2f, const float* __restrict__ b2,
    const float* __restrict__ AC,
    float* __restrict__ pSum, float* __restrict__ pSq,
    float* __restrict__ maxk)
{
    __shared__ __align__(16) short h1s[128*64];   // 16 KB, swizzled
    __shared__ __align__(16) short h2s[128*64];   // 16 KB
    __shared__ __align__(16) short w1s[8*64*8];   // 8 KB, frag order
    __shared__ __align__(16) short w2s[16*64*8];  // 16 KB
    __shared__ float sS[4][128];
    __shared__ float sQ[4][128];
    __shared__ float sM[4][128];

    const int tid = threadIdx.x;
    const int bid = blockIdx.x;

    // stage weight fragments (linear, conflict-free 16B chunks)
    {
        const uint4* s1 = (const uint4*)w1f;
        uint4* d1 = (uint4*)w1s;
        for (int i = tid; i < 512; i += 256) d1[i] = s1[i];
        if (DEPTH == 3) {
            const uint4* s2 = (const uint4*)w2f;
            uint4* d2 = (uint4*)w2s;
            for (int i = tid; i < 1024; i += 256) d2[i] = s2[i];
        }
    }

    // ---- Phase A: layer 1 on VALU, affine+relu, bf16, swizzled LDS store.
    {
        const int rloc = tid & 127;
        const int half = __builtin_amdgcn_readfirstlane(tid >> 7);
        const size_t rowg = (size_t)bid * 128 + rloc;
        const float* xr = x0 + rowg * ICH;
        float x[ICH];
#pragma unroll
        for (int c = 0; c < ICH; ++c) x[c] = xr[c];
        const float* w0h = w0 + half*32*ICH;
        const float* b0h = b0 + half*32;
        const float* Ah  = AC + half*32;
        const float* Ch  = AC + 64 + half*32;
        float h[32];
#pragma unroll
        for (int o = 0; o < 32; ++o) {
            float a = b0h[o];
#pragma unroll
            for (int c = 0; c < ICH; ++c) a += w0h[o*ICH + c] * x[c];
            h[o] = fmaxf(Ah[o]*a + Ch[o], 0.0f);
        }
#pragma unroll
        for (int q = 0; q < 4; ++q) {
            short8 v;
#pragma unroll
            for (int j = 0; j < 8; ++j) v[j] = f2bf(h[q*8 + j]);
            int byte = (rloc*128 + half*64 + q*16) ^ ((rloc & 7) << 4);
            *(short8*)((char*)h1s + byte) = v;
        }
    }
    __syncthreads();

    // ---- Phase B: layer 2 MFMA
    const int wv = tid >> 6;
    const int l  = tid & 63;
    const int lr = l & 15, lk = l >> 4;

    f32x4 acc2[2][4];
    const f32x4 fz = {0.f, 0.f, 0.f, 0.f};
#pragma unroll
    for (int m = 0; m < 2; ++m)
#pragma unroll
        for (int n = 0; n < 4; ++n) acc2[m][n] = fz;

    short8 afr[2][2];
#pragma unroll
    for (int m = 0; m < 2; ++m)
#pragma unroll
        for (int kb = 0; kb < 2; ++kb) {
            int row = wv*32 + m*16 + lr;
            int byte = (row*128 + (kb*4 + lk)*16) ^ ((row & 7) << 4);
            afr[m][kb] = *(short8*)((char*)h1s + byte);
        }
#pragma unroll
    for (int n = 0; n < 4; ++n) {
        short8 bf0 = *(short8*)(w1s + ((n*2+0)*64 + l)*8);
        short8 bf1 = *(short8*)(w1s + ((n*2+1)*64 + l)*8);
#pragma unroll
        for (int m = 0; m < 2; ++m) {
            acc2[m][n] = __builtin_amdgcn_mfma_f32_16x16x32_bf16(afr[m][0], bf0, acc2[m][n], 0, 0, 0);
            acc2[m][n] = __builtin_amdgcn_mfma_f32_16x16x32_bf16(afr[m][1], bf1, acc2[m][n], 0, 0, 0);
        }
    }
    // bias
#pragma unroll
    for (int n = 0; n < 4; ++n) {
        float bb = b1[n*16 + lr];
#pragma unroll
        for (int m = 0; m < 2; ++m)
#pragma unroll
            for (int r = 0; r < 4; ++r) acc2[m][n][r] += bb;
    }

    if (DEPTH == 2) {
#pragma unroll
        for (int n = 0; n < 4; ++n) {
            float s1 = 0.f, s2 = 0.f;
#pragma unroll
            for (int m = 0; m < 2; ++m)
#pragma unroll
                for (int r = 0; r < 4; ++r) {
                    float v = acc2[m][n][r];
                    s1 += v; s2 += v*v;
                }
            s1 += __shfl_xor(s1, 16, 64); s1 += __shfl_xor(s1, 32, 64);
            s2 += __shfl_xor(s2, 16, 64); s2 += __shfl_xor(s2, 32, 64);
            if (l < 16) { sS[wv][n*16 + l] = s1; sQ[wv][n*16 + l] = s2; }
        }
        __syncthreads();
        if (tid < OC2) {
            float a = 0.f, q = 0.f;
#pragma unroll
            for (int w = 0; w < 4; ++w) { a += sS[w][tid]; q += sQ[w][tid]; }
            pSum[(size_t)bid*OC2 + tid] = a;
            pSq [(size_t)bid*OC2 + tid] = q;
        }
        return;
    }

    // ---- DEPTH == 3: affine+relu -> bf16 h2 -> LDS (same swizzle)
#pragma unroll
    for (int n = 0; n < 4; ++n) {
        int c = n*16 + lr;
        float A2 = AC[128 + c], C2 = AC[192 + c];
#pragma unroll
        for (int m = 0; m < 2; ++m)
#pragma unroll
            for (int r = 0; r < 4; ++r) {
                float v = fmaxf(A2*acc2[m][n][r] + C2, 0.0f);
                int row = wv*32 + m*16 + lk*4 + r;
                int byte = (row*128 + c*2) ^ ((row & 7) << 4);
                *(short*)((char*)h2s + byte) = f2bf(v);
            }
    }
    __syncthreads();

    // ---- Phase C: layer 3 MFMA
    f32x4 acc3[2][8];
#pragma unroll
    for (int m = 0; m < 2; ++m)
#pragma unroll
        for (int n = 0; n < 8; ++n) acc3[m][n] = fz;

    short8 afr2[2][2];
#pragma unroll
    for (int m = 0; m < 2; ++m)
#pragma unroll
        for (int kb = 0; kb < 2; ++kb) {
            int row = wv*32 + m*16 + lr;
            int byte = (row*128 + (kb*4 + lk)*16) ^ ((row & 7) << 4);
            afr2[m][kb] = *(short8*)((char*)h2s + byte);
        }
#pragma unroll
    for (int n = 0; n < 8; ++n) {
        short8 bf0 = *(short8*)(w2s + ((n*2+0)*64 + l)*8);
        short8 bf1 = *(short8*)(w2s + ((n*2+1)*64 + l)*8);
#pragma unroll
        for (int m = 0; m < 2; ++m) {
            acc3[m][n] = __builtin_amdgcn_mfma_f32_16x16x32_bf16(afr2[m][0], bf0, acc3[m][n], 0, 0, 0);
            acc3[m][n] = __builtin_amdgcn_mfma_f32_16x16x32_bf16(afr2[m][1], bf1, acc3[m][n], 0, 0, 0);
        }
    }

    // stats + per-wave (32-row) col max
#pragma unroll
    for (int n = 0; n < 8; ++n) {
        float bb = b2[n*16 + lr];
        float s1 = 0.f, s2 = 0.f, mx = -3.0e38f;
#pragma unroll
        for (int m = 0; m < 2; ++m)
#pragma unroll
            for (int r = 0; r < 4; ++r) {
                float v = acc3[m][n][r] + bb;
                s1 += v; s2 += v*v; mx = fmaxf(mx, v);
            }
        s1 += __shfl_xor(s1, 16, 64); s1 += __shfl_xor(s1, 32, 64);
        s2 += __shfl_xor(s2, 16, 64); s2 += __shfl_xor(s2, 32, 64);
        mx = fmaxf(mx, __shfl_xor(mx, 16, 64));
        mx = fmaxf(mx, __shfl_xor(mx, 32, 64));
        if (l < 16) {
            sS[wv][n*16 + l] = s1;
            sQ[wv][n*16 + l] = s2;
            sM[wv][n*16 + l] = mx;
        }
    }
    __syncthreads();
    if (tid < OC3) {
        float a = 0.f, q = 0.f;
#pragma unroll
        for (int w = 0; w < 4; ++w) { a += sS[w][tid]; q += sQ[w][tid]; }
        pSum[(size_t)bid*OC3 + tid] = a;
        pSq [(size_t)bid*OC3 + tid] = q;
    }
    {
        int g = tid >> 7, c = tid & 127;   // 2 groups of 64 rows per block
        maxk[((size_t)bid*2 + g)*OC3 + c] = fmaxf(sM[2*g][c], sM[2*g+1][c]);
    }
}

// ---------------------------------------------------------------------------
// Finalize BN affine: A = g*rsqrt(var+eps), C = be - mean*A.
// ---------------------------------------------------------------------------
__global__ __launch_bounds__(256) void k_finalize(
    const float* __restrict__ pSum, const float* __restrict__ pSq,
    const float* __restrict__ g, const float* __restrict__ be,
    float* __restrict__ A, float* __restrict__ C, int OC, int nblk)
{
    const int o = blockIdx.x, tid = threadIdx.x;
    float s1 = 0.f, s2 = 0.f;
    for (int i = tid; i < nblk; i += 256) {
        s1 += pSum[(size_t)i*OC + o];
        s2 += pSq [(size_t)i*OC + o];
    }
    __shared__ float r1[256], r2[256];
    r1[tid] = s1; r2[tid] = s2;
    __syncthreads();
    for (int s = 128; s > 0; s >>= 1) {
        if (tid < s) { r1[tid] += r1[tid+s]; r2[tid] += r2[tid+s]; }
        __syncthreads();
    }
    if (tid == 0) {
        float mean = r1[0] * (1.0f / NTOTF);
        float var  = r2[0] * (1.0f / NTOTF) - mean*mean;
        float a = g[o] / sqrtf(var + 1e-5f);
        A[o] = a;
        C[o] = be[o] - mean * a;
    }
}

// ---------------------------------------------------------------------------
// Final output: out1[b][ch][s] = relu(A3[ch]*maxk[b*NPT+s][ch] + C3[ch])
// ---------------------------------------------------------------------------
__global__ __launch_bounds__(256) void k_out(const float* __restrict__ maxk,
                                             const float* __restrict__ A,
                                             const float* __restrict__ C,
                                             float* __restrict__ out1)
{
    int idx = blockIdx.x * 256 + threadIdx.x;
    int s  = idx & (NPT - 1);
    int ch = (idx >> 10) & (OC3 - 1);
    int b  = idx >> 17;
    float v = maxk[((size_t)(b * NPT + s)) * OC3 + ch];
    out1[idx] = fmaxf(A[ch] * v + C[ch], 0.0f);
}

// ---------------------------------------------------------------------------
extern "C" void kernel_launch(void* const* d_in, const int* in_sizes, int n_in,
                              void* d_out, int out_size, void* d_ws, size_t ws_size,
                              hipStream_t stream)
{
    const float* xyz = (const float*)d_in[0];
    const float* pts = (const float*)d_in[1];
    const float* w0  = (const float*)d_in[2];
    const float* b0  = (const float*)d_in[3];
    const float* g0  = (const float*)d_in[4];
    const float* be0 = (const float*)d_in[5];
    const float* w1  = (const float*)d_in[6];
    const float* b1  = (const float*)d_in[7];
    const float* g1  = (const float*)d_in[8];
    const float* be1 = (const float*)d_in[9];
    const float* w2  = (const float*)d_in[10];
    const float* b2  = (const float*)d_in[11];
    const float* g2  = (const float*)d_in[12];
    const float* be2 = (const float*)d_in[13];

    float* out0 = (float*)d_out;                     // new_xyz (16,1024,3)
    float* out1 = out0 + (size_t)NBATCH*NPT*3;       // new_points (16,128,1024)

    // Workspace layout (floats). ~52 MB.
    float* ws   = (float*)d_ws;
    float* x0   = ws;                                  // 9,437,184
    float* pSum = x0   + (size_t)NROWS*ICH;            // 1,048,576 (8192*128)
    float* pSq  = pSum + (size_t)NBLK23*OC3;           // 1,048,576
    float* AC   = pSq  + (size_t)NBLK23*OC3;           // 512
    float* maxk = AC + 512;                            // 2,097,152
    short* w1f  = (short*)(maxk + (size_t)NBATCH*NPT*OC3);   // 4096 shorts
    short* w2f  = w1f + 8*64*8;                        // 8192 shorts

    k_prep <<<6, 256, 0, stream>>>(w1, w2, w1f, w2f);
    k_fps  <<<NBATCH, 128, 0, stream>>>(xyz, out0);
    k_ballq<<<(NBATCH*NPT)/4, 256, 0, stream>>>(xyz, pts, out0, x0);

    k_mlp1<<<NBLK1, 256, 0, stream>>>(x0, w0, b0, pSum, pSq);
    k_finalize<<<OC1, 256, 0, stream>>>(pSum, pSq, g0, be0, AC+0,   AC+64,  OC1, NBLK1);
    k_mlp23<2><<<NBLK23, 256, 0, stream>>>(x0, w0,b0, w1f,b1, w2f,b2, AC, pSum, pSq, maxk);
    k_finalize<<<OC2, 256, 0, stream>>>(pSum, pSq, g1, be1, AC+128, AC+192, OC2, NBLK23);
    k_mlp23<3><<<NBLK23, 256, 0, stream>>>(x0, w0,b0, w1f,b1, w2f,b2, AC, pSum, pSq, maxk);
    k_finalize<<<OC3, 256, 0, stream>>>(pSum, pSq, g2, be2, AC+256, AC+384, OC3, NBLK23);

    k_out<<<(NBATCH*OC3*NPT)/256, 256, 0, stream>>>(maxk, AC+256, AC+384, out1);
}

// Round 9
// 902.942 us; speedup vs baseline: 1.3262x; 1.3066x over previous
//
#include <hip/hip_runtime.h>
#include <hip/hip_bf16.h>
#include <stdint.h>

// Problem constants
#define NBATCH 16
#define NPTS   4096
#define NPT    1024     // NPOINT
#define NSMP   64       // NSAMPLE
#define R2     0.04f    // RADIUS^2
#define ICH    9
#define OC1    64
#define OC2    64
#define OC3    128
#define NROWS  (NBATCH*NPT*NSMP)   // 1048576
#define NBLK1  (NROWS/256)         // 4096 blocks, pass-1
#define NBLK23 (NROWS/128)         // 8192 blocks, pass-2/3
#define NTOTF  1048576.0f

typedef __attribute__((ext_vector_type(8))) short short8;   // 8 bf16 (4 VGPR)
typedef __attribute__((ext_vector_type(4))) float f32x4;
typedef __attribute__((ext_vector_type(2))) float f32x2;    // v_pk_* pair

__device__ __forceinline__ short f2bf(float f) {
    __hip_bfloat16 h = __float2bfloat16(f);
    return *reinterpret_cast<short*>(&h);
}

// f32 max-combine with a DPP-moved copy (row_shr / row_bcast reduction).
// old = self, bound_ctrl = false -> disabled lanes combine with themselves.
// Validated in R6 (absmax unchanged).
#define DPP32_MAXF(v, CTRL, RM) do {                                         \
    int _mv = __builtin_amdgcn_update_dpp(__float_as_int(v),                 \
                                          __float_as_int(v),                 \
                                          CTRL, RM, 0xF, false);             \
    (v) = fmaxf((v), __int_as_float(_mv));                                   \
} while (0)

// ---------------------------------------------------------------------------
// Kernel 1: farthest point sampling, v8. R5's proven structure (one block
// per batch, 256 thr = 4 waves, 16 pts/lane, SINGLE barrier per step) with
// a lightweight reduction:
//   dist update (56 pk ops) -> per-lane value tree (8 ops -> lmax) ->
//   descending equality scan (min local idx, overlaps DPP chain) ->
//   6-level fused f32 DPP wave max -> readlane(63) SGPR broadcast ->
//   ballot(lmax==wmax) -> ffsll -> readlane(cand, winner) ->
//   lane0 writes u64 (wmax_bits, ~idx) -> barrier -> 3 u64 max -> far.
// Contiguous per-lane ownership (p = tid*16+j): lowest ballot lane owns the
// minimum global index among max-achieving lanes; descending scan gives the
// min index within the lane; cross-wave u64 (value, ~idx) max gives min
// index on value ties -> first-occurrence argmax, identical to jnp.argmax
// and to all previously passing versions. Distance ops are the same packed
// IEEE ops -> same bits -> identical selection sequence.
// ---------------------------------------------------------------------------
__global__ __launch_bounds__(256) void k_fps(const float* __restrict__ xyz,
                                             float* __restrict__ newxyz)
{
    const int b    = blockIdx.x;
    const int tid  = threadIdx.x;
    const int wv   = tid >> 6;
    const int lane = tid & 63;
    const float* X = xyz + (size_t)b * NPTS * 3;

    __shared__ __align__(16) float sxyz[NPTS * 4];   // 64 KB packed points
    __shared__ float scf[NPT * 3];                   // 12 KB centroid trace
    __shared__ unsigned long long sKey[2][4];        // dbuf wave partials

    const int p0 = tid * 16;                 // 16 contiguous points/thread
    f32x2 px[8], py[8], pz[8], dd[8];
    {
        // 16 pts = 48 floats = 12 aligned float4 loads (R8-validated loader)
        const f32x4* src = (const f32x4*)(X + (size_t)p0 * 3);
        float c[48];
#pragma unroll
        for (int q = 0; q < 12; ++q) *(f32x4*)&c[q*4] = src[q];
#pragma unroll
        for (int m = 0; m < 8; ++m) {
            px[m] = (f32x2){c[6*m+0], c[6*m+3]};
            py[m] = (f32x2){c[6*m+1], c[6*m+4]};
            pz[m] = (f32x2){c[6*m+2], c[6*m+5]};
            dd[m] = (f32x2){1e10f, 1e10f};           // reference init
        }
#pragma unroll
        for (int j = 0; j < 16; ++j) {
            *(f32x4*)&sxyz[(p0 + j) * 4] =
                (f32x4){c[3*j+0], c[3*j+1], c[3*j+2], 0.f};
        }
    }
    __syncthreads();

    // initial centroid = point 0 (same floats as X[0..2])
    float cx = sxyz[0], cy = sxyz[1], cz = sxyz[2];

    for (int it = 0; it < NPT; ++it) {
        const int buf = it & 1;
        if (tid == 0) {                      // LDS-only trace write
            scf[it*3+0] = cx; scf[it*3+1] = cy; scf[it*3+2] = cz;
        }
        const f32x2 c2x = (f32x2){cx, cx};
        const f32x2 c2y = (f32x2){cy, cy};
        const f32x2 c2z = (f32x2){cz, cz};
#pragma unroll
        for (int m = 0; m < 8; ++m) {
            f32x2 dx = px[m] - c2x, dy = py[m] - c2y, dz = pz[m] - c2z;
            f32x2 d  = dx*dx + dy*dy + dz*dz;        // same per-elem IEEE ops
            dd[m] = __builtin_elementwise_min(dd[m], d);
        }
        // per-lane value max tree (exact: max associative)
        f32x2 t0 = __builtin_elementwise_max(dd[0], dd[1]);
        f32x2 t1 = __builtin_elementwise_max(dd[2], dd[3]);
        f32x2 t2 = __builtin_elementwise_max(dd[4], dd[5]);
        f32x2 t3 = __builtin_elementwise_max(dd[6], dd[7]);
        f32x2 u0 = __builtin_elementwise_max(t0, t1);
        f32x2 u1 = __builtin_elementwise_max(t2, t3);
        f32x2 v  = __builtin_elementwise_max(u0, u1);
        const float lmax = fmaxf(v.x, v.y);

        // descending equality scan: last hit = smallest local index.
        // Overlaps the DPP chain below (independent instructions).
        unsigned cand = 0u;
#pragma unroll
        for (int m = 7; m >= 0; --m) {
            if (dd[m].y == lmax) cand = 0xFFFFFFFFu - (unsigned)(p0 + 2*m + 1);
            if (dd[m].x == lmax) cand = 0xFFFFFFFFu - (unsigned)(p0 + 2*m + 0);
        }

        // 6-level fused f32 DPP wave max -> lane 63
        float wmax = lmax;
        DPP32_MAXF(wmax, 0x111, 0xF);
        DPP32_MAXF(wmax, 0x112, 0xF);
        DPP32_MAXF(wmax, 0x114, 0xF);
        DPP32_MAXF(wmax, 0x118, 0xF);
        DPP32_MAXF(wmax, 0x142, 0xA);
        DPP32_MAXF(wmax, 0x143, 0xC);
        // broadcast via SGPR
        wmax = __int_as_float(
            __builtin_amdgcn_readlane(__float_as_int(wmax), 63));
        // winner = lowest lane achieving wmax (= min global index, since
        // lane ownership is contiguous and ordered)
        unsigned long long bmask = __ballot(lmax == wmax);
        int wl = __ffsll((unsigned long long)bmask) - 1;
        unsigned wcand = (unsigned)__builtin_amdgcn_readlane((int)cand, wl);

        if (lane == 0)
            sKey[buf][wv] =
                ((unsigned long long)__float_as_uint(wmax) << 32) | wcand;
        __syncthreads();                     // single barrier per step
        unsigned long long k0 = sKey[buf][0];
        unsigned long long k1 = sKey[buf][1];
        unsigned long long k2 = sKey[buf][2];
        unsigned long long k3 = sKey[buf][3];
        unsigned long long m01 = k0 > k1 ? k0 : k1;
        unsigned long long m23 = k2 > k3 ? k2 : k3;
        unsigned long long bb  = m01 > m23 ? m01 : m23;
        const int far = (int)(0xFFFFFFFFu - (unsigned)(bb & 0xFFFFFFFFull));
        const f32x4 c4 = *(const f32x4*)&sxyz[far*4];   // one ds_read_b128
        cx = c4.x; cy = c4.y; cz = c4.z;
    }

    __syncthreads();
    // coalesced epilogue dump of the centroid trace
    float* outb = newxyz + (size_t)b * NPT * 3;
    for (int i = tid; i < NPT*3; i += 256) outb[i] = scf[i];
}

// ---------------------------------------------------------------------------
// Kernel 2: ball query + gather (unchanged). x0[row][9] f32.
// ---------------------------------------------------------------------------
__global__ __launch_bounds__(256) void k_ballq(const float* __restrict__ xyz,
                                               const float* __restrict__ pts,
                                               const float* __restrict__ newxyz,
                                               float* __restrict__ x0)
{
    const int wave = threadIdx.x >> 6;
    const int lane = threadIdx.x & 63;
    const int g = blockIdx.x * 4 + wave;
    const int b = g >> 10;
    const float* X = xyz + (size_t)b * NPTS * 3;
    const float* P = pts + (size_t)b * NPTS * 6;
    const float cx = newxyz[(size_t)g*3+0];
    const float cy = newxyz[(size_t)g*3+1];
    const float cz = newxyz[(size_t)g*3+2];
    const float sn = cx*cx + cy*cy + cz*cz;

    __shared__ int sFirst[4];
    int total = 0;
    for (int chunk = 0; chunk < NPTS/64; ++chunk) {
        int p = chunk*64 + lane;
        float x = X[p*3+0], y = X[p*3+1], z = X[p*3+2];
        float sp  = x*x + y*y + z*z;
        float dot = cx*x + cy*y + cz*z;
        float sqr = (sn + sp) - 2.0f*dot;
        bool inb = !(sqr > R2);
        unsigned long long mask = __ballot(inb);
        int before = __popcll(mask & ((1ull << lane) - 1ull));
        int pos = total + before;
        if (inb && pos < NSMP) {
            if (pos == 0) sFirst[wave] = p;
            float* row = x0 + ((size_t)g * NSMP + pos) * ICH;
            row[0] = x - cx; row[1] = y - cy; row[2] = z - cz;
#pragma unroll
            for (int c = 0; c < 6; ++c) row[3+c] = P[(size_t)p*6 + c];
        }
        total += (int)__popcll(mask);
        if (total >= NSMP) break;
    }
    if (total < NSMP) {
        int first = sFirst[wave];
        float x = X[first*3+0], y = X[first*3+1], z = X[first*3+2];
        float r0 = x - cx, r1 = y - cy, r2 = z - cz;
        float q0 = P[(size_t)first*6+0], q1 = P[(size_t)first*6+1], q2 = P[(size_t)first*6+2];
        float q3 = P[(size_t)first*6+3], q4 = P[(size_t)first*6+4], q5 = P[(size_t)first*6+5];
        for (int slot = total + lane; slot < NSMP; slot += 64) {
            float* row = x0 + ((size_t)g * NSMP + slot) * ICH;
            row[0]=r0; row[1]=r1; row[2]=r2;
            row[3]=q0; row[4]=q1; row[5]=q2; row[6]=q3; row[7]=q4; row[8]=q5;
        }
    }
}

// ---------------------------------------------------------------------------
// Weight prep: pack w1 (64x64) and w2 (128x64) into bf16 MFMA B-fragment
// order. Frag f = n*2 + kblk; entry (lane l, j): w[(n*16+(l&15))*64 +
// kblk*32 + (l>>4)*8 + j].
// ---------------------------------------------------------------------------
__global__ __launch_bounds__(256) void k_prep(const float* __restrict__ w1,
                                              const float* __restrict__ w2,
                                              short* __restrict__ w1f,
                                              short* __restrict__ w2f)
{
    int t = blockIdx.x * 256 + threadIdx.x;
    if (t < 8*64) {
        int f = t >> 6, l = t & 63;
        int n = f >> 1, kb = f & 1;
        int col = n*16 + (l & 15);
        int k0  = kb*32 + (l >> 4)*8;
#pragma unroll
        for (int j = 0; j < 8; ++j)
            w1f[((size_t)t)*8 + j] = f2bf(w1[col*64 + k0 + j]);
    } else if (t < 8*64 + 16*64) {
        int t2 = t - 8*64;
        int f = t2 >> 6, l = t2 & 63;
        int n = f >> 1, kb = f & 1;
        int col = n*16 + (l & 15);
        int k0  = kb*32 + (l >> 4)*8;
#pragma unroll
        for (int j = 0; j < 8; ++j)
            w2f[((size_t)t2)*8 + j] = f2bf(w2[col*64 + k0 + j]);
    }
}

// ---------------------------------------------------------------------------
// Pass-1 stats: 256 rows/block, f32 VALU layer 1, LDS-transposed per-channel
// sum/sumsq partials.
// ---------------------------------------------------------------------------
__global__ __launch_bounds__(256) void k_mlp1(
    const float* __restrict__ x0,
    const float* __restrict__ w0, const float* __restrict__ b0,
    float* __restrict__ pSum, float* __restrict__ pSq)
{
    __shared__ float staged[32 * 256];
    const int tid = threadIdx.x;
    const int bid = blockIdx.x;
    const size_t row = (size_t)bid * 256 + tid;

    float x[ICH];
    const float* xr = x0 + row * ICH;
#pragma unroll
    for (int c = 0; c < ICH; ++c) x[c] = xr[c];

    float h1[OC1];
#pragma unroll
    for (int o = 0; o < OC1; ++o) {
        float a = b0[o];
#pragma unroll
        for (int c = 0; c < ICH; ++c) a += w0[o*ICH + c] * x[c];
        h1[o] = a;
    }
#pragma unroll
    for (int cb = 0; cb < OC1; cb += 32) {
        __syncthreads();
#pragma unroll
        for (int o = 0; o < 32; ++o) staged[o*256 + tid] = h1[cb + o];
        __syncthreads();
        const int ch = tid >> 3, seg = tid & 7;
        const float* col = staged + ch*256 + seg*32;
        float s1 = 0.f, s2 = 0.f;
#pragma unroll
        for (int i = 0; i < 32; ++i) {
            float vv = col[(i + tid) & 31];
            s1 += vv; s2 += vv*vv;
        }
#pragma unroll
        for (int m = 1; m < 8; m <<= 1) {
            s1 += __shfl_xor(s1, m, 64);
            s2 += __shfl_xor(s2, m, 64);
        }
        if (seg == 0) {
            pSum[(size_t)bid*OC1 + cb + ch] = s1;
            pSq [(size_t)bid*OC1 + cb + ch] = s2;
        }
    }
}

// ---------------------------------------------------------------------------
// MFMA passes 2/3 (unchanged from passing round-3 version).
// ---------------------------------------------------------------------------
template<int DEPTH>
__global__ __launch_bounds__(256) void k_mlp23(
    const float* __restrict__ x0,
    const float* __restrict__ w0, const float* __restrict__ b0,
    const short* __restrict__ w1f, const float* __restrict__ b1,
    const short* __restrict__ w2f, const float* __restrict__ b2,
    const float* __restrict__ AC,
    float* __restrict__ pSum, float* __restrict__ pSq,
    float* __restrict__ maxk)
{
    __shared__ __align__(16) short h1s[128*64];   // 16 KB, swizzled
    __shared__ __align__(16) short h2s[128*64];   // 16 KB
    __shared__ __align__(16) short w1s[8*64*8];   // 8 KB, frag order
    __shared__ __align__(16) short w2s[16*64*8];  // 16 KB
    __shared__ float sS[4][128];
    __shared__ float sQ[4][128];
    __shared__ float sM[4][128];

    const int tid = threadIdx.x;
    const int bid = blockIdx.x;

    // stage weight fragments (linear, conflict-free 16B chunks)
    {
        const uint4* s1 = (const uint4*)w1f;
        uint4* d1 = (uint4*)w1s;
        for (int i = tid; i < 512; i += 256) d1[i] = s1[i];
        if (DEPTH == 3) {
            const uint4* s2 = (const uint4*)w2f;
            uint4* d2 = (uint4*)w2s;
            for (int i = tid; i < 1024; i += 256) d2[i] = s2[i];
        }
    }

    // ---- Phase A: layer 1 on VALU, affine+relu, bf16, swizzled LDS store.
    {
        const int rloc = tid & 127;
        const int half = __builtin_amdgcn_readfirstlane(tid >> 7);
        const size_t rowg = (size_t)bid * 128 + rloc;
        const float* xr = x0 + rowg * ICH;
        float x[ICH];
#pragma unroll
        for (int c = 0; c < ICH; ++c) x[c] = xr[c];
        const float* w0h = w0 + half*32*ICH;
        const float* b0h = b0 + half*32;
        const float* Ah  = AC + half*32;
        const float* Ch  = AC + 64 + half*32;
        float h[32];
#pragma unroll
        for (int o = 0; o < 32; ++o) {
            float a = b0h[o];
#pragma unroll
            for (int c = 0; c < ICH; ++c) a += w0h[o*ICH + c] * x[c];
            h[o] = fmaxf(Ah[o]*a + Ch[o], 0.0f);
        }
#pragma unroll
        for (int q = 0; q < 4; ++q) {
            short8 v;
#pragma unroll
            for (int j = 0; j < 8; ++j) v[j] = f2bf(h[q*8 + j]);
            int byte = (rloc*128 + half*64 + q*16) ^ ((rloc & 7) << 4);
            *(short8*)((char*)h1s + byte) = v;
        }
    }
    __syncthreads();

    // ---- Phase B: layer 2 MFMA
    const int wv = tid >> 6;
    const int l  = tid & 63;
    const int lr = l & 15, lk = l >> 4;

    f32x4 acc2[2][4];
    const f32x4 fz = {0.f, 0.f, 0.f, 0.f};
#pragma unroll
    for (int m = 0; m < 2; ++m)
#pragma unroll
        for (int n = 0; n < 4; ++n) acc2[m][n] = fz;

    short8 afr[2][2];
#pragma unroll
    for (int m = 0; m < 2; ++m)
#pragma unroll
        for (int kb = 0; kb < 2; ++kb) {
            int row = wv*32 + m*16 + lr;
            int byte = (row*128 + (kb*4 + lk)*16) ^ ((row & 7) << 4);
            afr[m][kb] = *(short8*)((char*)h1s + byte);
        }
#pragma unroll
    for (int n = 0; n < 4; ++n) {
        short8 bf0 = *(short8*)(w1s + ((n*2+0)*64 + l)*8);
        short8 bf1 = *(short8*)(w1s + ((n*2+1)*64 + l)*8);
#pragma unroll
        for (int m = 0; m < 2; ++m) {
            acc2[m][n] = __builtin_amdgcn_mfma_f32_16x16x32_bf16(afr[m][0], bf0, acc2[m][n], 0, 0, 0);
            acc2[m][n] = __builtin_amdgcn_mfma_f32_16x16x32_bf16(afr[m][1], bf1, acc2[m][n], 0, 0, 0);
        }
    }
    // bias
#pragma unroll
    for (int n = 0; n < 4; ++n) {
        float bb = b1[n*16 + lr];
#pragma unroll
        for (int m = 0; m < 2; ++m)
#pragma unroll
            for (int r = 0; r < 4; ++r) acc2[m][n][r] += bb;
    }

    if (DEPTH == 2) {
#pragma unroll
        for (int n = 0; n < 4; ++n) {
            float s1 = 0.f, s2 = 0.f;
#pragma unroll
            for (int m = 0; m < 2; ++m)
#pragma unroll
                for (int r = 0; r < 4; ++r) {
                    float v = acc2[m][n][r];
                    s1 += v; s2 += v*v;
                }
            s1 += __shfl_xor(s1, 16, 64); s1 += __shfl_xor(s1, 32, 64);
            s2 += __shfl_xor(s2, 16, 64); s2 += __shfl_xor(s2, 32, 64);
            if (l < 16) { sS[wv][n*16 + l] = s1; sQ[wv][n*16 + l] = s2; }
        }
        __syncthreads();
        if (tid < OC2) {
            float a = 0.f, q = 0.f;
#pragma unroll
            for (int w = 0; w < 4; ++w) { a += sS[w][tid]; q += sQ[w][tid]; }
            pSum[(size_t)bid*OC2 + tid] = a;
            pSq [(size_t)bid*OC2 + tid] = q;
        }
        return;
    }

    // ---- DEPTH == 3: affine+relu -> bf16 h2 -> LDS (same swizzle)
#pragma unroll
    for (int n = 0; n < 4; ++n) {
        int c = n*16 + lr;
        float A2 = AC[128 + c], C2 = AC[192 + c];
#pragma unroll
        for (int m = 0; m < 2; ++m)
#pragma unroll
            for (int r = 0; r < 4; ++r) {
                float v = fmaxf(A2*acc2[m][n][r] + C2, 0.0f);
                int row = wv*32 + m*16 + lk*4 + r;
                int byte = (row*128 + c*2) ^ ((row & 7) << 4);
                *(short*)((char*)h2s + byte) = f2bf(v);
            }
    }
    __syncthreads();

    // ---- Phase C: layer 3 MFMA
    f32x4 acc3[2][8];
#pragma unroll
    for (int m = 0; m < 2; ++m)
#pragma unroll
        for (int n = 0; n < 8; ++n) acc3[m][n] = fz;

    short8 afr2[2][2];
#pragma unroll
    for (int m = 0; m < 2; ++m)
#pragma unroll
        for (int kb = 0; kb < 2; ++kb) {
            int row = wv*32 + m*16 + lr;
            int byte = (row*128 + (kb*4 + lk)*16) ^ ((row & 7) << 4);
            afr2[m][kb] = *(short8*)((char*)h2s + byte);
        }
#pragma unroll
    for (int n = 0; n < 8; ++n) {
        short8 bf0 = *(short8*)(w2s + ((n*2+0)*64 + l)*8);
        short8 bf1 = *(short8*)(w2s + ((n*2+1)*64 + l)*8);
#pragma unroll
        for (int m = 0; m < 2; ++m) {
            acc3[m][n] = __builtin_amdgcn_mfma_f32_16x16x32_bf16(afr2[m][0], bf0, acc3[m][n], 0, 0, 0);
            acc3[m][n] = __builtin_amdgcn_mfma_f32_16x16x32_bf16(afr2[m][1], bf1, acc3[m][n], 0, 0, 0);
        }
    }

    // stats + per-wave (32-row) col max
#pragma unroll
    for (int n = 0; n < 8; ++n) {
        float bb = b2[n*16 + lr];
        float s1 = 0.f, s2 = 0.f, mx = -3.0e38f;
#pragma unroll
        for (int m = 0; m < 2; ++m)
#pragma unroll
            for (int r = 0; r < 4; ++r) {
                float v = acc3[m][n][r] + bb;
                s1 += v; s2 += v*v; mx = fmaxf(mx, v);
            }
        s1 += __shfl_xor(s1, 16, 64); s1 += __shfl_xor(s1, 32, 64);
        s2 += __shfl_xor(s2, 16, 64); s2 += __shfl_xor(s2, 32, 64);
        mx = fmaxf(mx, __shfl_xor(mx, 16, 64));
        mx = fmaxf(mx, __shfl_xor(mx, 32, 64));
        if (l < 16) {
            sS[wv][n*16 + l] = s1;
            sQ[wv][n*16 + l] = s2;
            sM[wv][n*16 + l] = mx;
        }
    }
    __syncthreads();
    if (tid < OC3) {
        float a = 0.f, q = 0.f;
#pragma unroll
        for (int w = 0; w < 4; ++w) { a += sS[w][tid]; q += sQ[w][tid]; }
        pSum[(size_t)bid*OC3 + tid] = a;
        pSq [(size_t)bid*OC3 + tid] = q;
    }
    {
        int g = tid >> 7, c = tid & 127;   // 2 groups of 64 rows per block
        maxk[((size_t)bid*2 + g)*OC3 + c] = fmaxf(sM[2*g][c], sM[2*g+1][c]);
    }
}

// ---------------------------------------------------------------------------
// Finalize BN affine: A = g*rsqrt(var+eps), C = be - mean*A.
// ---------------------------------------------------------------------------
__global__ __launch_bounds__(256) void k_finalize(
    const float* __restrict__ pSum, const float* __restrict__ pSq,
    const float* __restrict__ g, const float* __restrict__ be,
    float* __restrict__ A, float* __restrict__ C, int OC, int nblk)
{
    const int o = blockIdx.x, tid = threadIdx.x;
    float s1 = 0.f, s2 = 0.f;
    for (int i = tid; i < nblk; i += 256) {
        s1 += pSum[(size_t)i*OC + o];
        s2 += pSq [(size_t)i*OC + o];
    }
    __shared__ float r1[256], r2[256];
    r1[tid] = s1; r2[tid] = s2;
    __syncthreads();
    for (int s = 128; s > 0; s >>= 1) {
        if (tid < s) { r1[tid] += r1[tid+s]; r2[tid] += r2[tid+s]; }
        __syncthreads();
    }
    if (tid == 0) {
        float mean = r1[0] * (1.0f / NTOTF);
        float var  = r2[0] * (1.0f / NTOTF) - mean*mean;
        float a = g[o] / sqrtf(var + 1e-5f);
        A[o] = a;
        C[o] = be[o] - mean * a;
    }
}

// ---------------------------------------------------------------------------
// Final output: out1[b][ch][s] = relu(A3[ch]*maxk[b*NPT+s][ch] + C3[ch])
// ---------------------------------------------------------------------------
__global__ __launch_bounds__(256) void k_out(const float* __restrict__ maxk,
                                             const float* __restrict__ A,
                                             const float* __restrict__ C,
                                             float* __restrict__ out1)
{
    int idx = blockIdx.x * 256 + threadIdx.x;
    int s  = idx & (NPT - 1);
    int ch = (idx >> 10) & (OC3 - 1);
    int b  = idx >> 17;
    float v = maxk[((size_t)(b * NPT + s)) * OC3 + ch];
    out1[idx] = fmaxf(A[ch] * v + C[ch], 0.0f);
}

// ---------------------------------------------------------------------------
extern "C" void kernel_launch(void* const* d_in, const int* in_sizes, int n_in,
                              void* d_out, int out_size, void* d_ws, size_t ws_size,
                              hipStream_t stream)
{
    const float* xyz = (const float*)d_in[0];
    const float* pts = (const float*)d_in[1];
    const float* w0  = (const float*)d_in[2];
    const float* b0  = (const float*)d_in[3];
    const float* g0  = (const float*)d_in[4];
    const float* be0 = (const float*)d_in[5];
    const float* w1  = (const float*)d_in[6];
    const float* b1  = (const float*)d_in[7];
    const float* g1  = (const float*)d_in[8];
    const float* be1 = (const float*)d_in[9];
    const float* w2  = (const float*)d_in[10];
    const float* b2  = (const float*)d_in[11];
    const float* g2  = (const float*)d_in[12];
    const float* be2 = (const float*)d_in[13];

    float* out0 = (float*)d_out;                     // new_xyz (16,1024,3)
    float* out1 = out0 + (size_t)NBATCH*NPT*3;       // new_points (16,128,1024)

    // Workspace layout (floats). ~52 MB.
    float* ws   = (float*)d_ws;
    float* x0   = ws;                                  // 9,437,184
    float* pSum = x0   + (size_t)NROWS*ICH;            // 1,048,576 (8192*128)
    float* pSq  = pSum + (size_t)NBLK23*OC3;           // 1,048,576
    float* AC   = pSq  + (size_t)NBLK23*OC3;           // 512
    float* maxk = AC + 512;                            // 2,097,152
    short* w1f  = (short*)(maxk + (size_t)NBATCH*NPT*OC3);   // 4096 shorts
    short* w2f  = w1f + 8*64*8;                        // 8192 shorts

    k_prep <<<6, 256, 0, stream>>>(w1, w2, w1f, w2f);
    k_fps  <<<NBATCH, 256, 0, stream>>>(xyz, out0);
    k_ballq<<<(NBATCH*NPT)/4, 256, 0, stream>>>(xyz, pts, out0, x0);

    k_mlp1<<<NBLK1, 256, 0, stream>>>(x0, w0, b0, pSum, pSq);
    k_finalize<<<OC1, 256, 0, stream>>>(pSum, pSq, g0, be0, AC+0,   AC+64,  OC1, NBLK1);
    k_mlp23<2><<<NBLK23, 256, 0, stream>>>(x0, w0,b0, w1f,b1, w2f,b2, AC, pSum, pSq, maxk);
    k_finalize<<<OC2, 256, 0, stream>>>(pSum, pSq, g1, be1, AC+128, AC+192, OC2, NBLK23);
    k_mlp23<3><<<NBLK23, 256, 0, stream>>>(x0, w0,b0, w1f,b1, w2f,b2, AC, pSum, pSq, maxk);
    k_finalize<<<OC3, 256, 0, stream>>>(pSum, pSq, g2, be2, AC+256, AC+384, OC3, NBLK23);

    k_out<<<(NBATCH*OC3*NPT)/256, 256, 0, stream>>>(maxk, AC+256, AC+384, out1);
}